// Round 5
// baseline (265.933 us; speedup 1.0000x reference)
//
#include <hip/hip_runtime.h>

typedef _Float16 half8 __attribute__((ext_vector_type(8)));
typedef _Float16 half4 __attribute__((ext_vector_type(4)));
typedef float f32x4 __attribute__((ext_vector_type(4)));
typedef float f32x16 __attribute__((ext_vector_type(16)));

#define SA 320           // LDS act stride in halves (40 chunks of 8)
#define MROW 128         // rows per block = 32 queries x 4 shifts
// LDS act buffer: 128*320*2 = 81920 B -> 2 blocks/CU

// ---------------------------------------------------------------------------
// Prep: features -> featT [px][32] fp16; weights -> Wt[n][k] fp16.
// All weight READS are lane-coalesced (n = i&255); the transpose scatter is
// on the store side (stores don't stall the wave).
// W1 cols permuted col=k*32+c; cols 288..291 = rel/cell rows; 292..319 = 0.
// ---------------------------------------------------------------------------
__global__ void liif_prep(const float* __restrict__ feat,
                          const float* __restrict__ w1, const float* __restrict__ w2,
                          const float* __restrict__ w3, const float* __restrict__ w4,
                          const float* __restrict__ w5,
                          _Float16* __restrict__ featT,
                          _Float16* __restrict__ wt1, _Float16* __restrict__ wt2,
                          _Float16* __restrict__ wt3, _Float16* __restrict__ wt4,
                          _Float16* __restrict__ wt5) {
  const int blk = blockIdx.x, tid = threadIdx.x;
  if (blk < 256) {                         // featT: thread = 1 px, 64 B contig write
    const int px = blk * 256 + tid;
    _Float16 v[32];
#pragma unroll
    for (int c = 0; c < 32; ++c) v[c] = (_Float16)feat[(c << 16) + px];
    half8* dst = (half8*)(featT + px * 32);
#pragma unroll
    for (int j = 0; j < 4; ++j) dst[j] = *(half8*)(v + j * 8);
    return;
  }
  int i = (blk - 256) * 256 + tid;
  if (i < 81920) {                         // wt1 [256n][320col]; read coalesced in n
    const int n = i & 255, col = i >> 8;
    float v = 0.f;
    if (col < 288) v = w1[((col & 31) * 9 + (col >> 5)) * 256 + n];
    else if (col < 292) v = w1[col * 256 + n];
    wt1[n * 320 + col] = (_Float16)v;
    return;
  }
  i -= 81920;
  if (i < 196608) {                        // wt2..wt4 [256n][256k]; read coalesced in n
    const int li = i >> 16, r = i & 65535;
    const int k = r >> 8, n = r & 255;
    const float* w = (li == 0) ? w2 : ((li == 1) ? w3 : w4);
    _Float16* wt = (li == 0) ? wt2 : ((li == 1) ? wt3 : wt4);
    wt[n * 256 + k] = (_Float16)w[k * 256 + n];
    return;
  }
  i -= 196608;
  if (i < 4096) {                          // wt5: [16][256], rows 3..15 zero
    const int f = i >> 8, k = i & 255;
    wt5[f * 256 + k] = (f < 3) ? (_Float16)w5[k * 3 + f] : (_Float16)0.f;
  }
}

// per-row geometry (exact-rounded to match reference)
__device__ __forceinline__ void row_params(int r, const float* __restrict__ loc,
                                           const float* __restrict__ cell,
                                           int& iy, int& ix, float& rel0v, float& rel1v,
                                           float& c0v, float& c1v) {
  const int q = r >> 2, s = r & 3;
  const float loc0 = loc[q * 2 + 0], loc1 = loc[q * 2 + 1];
  const float shy = (s & 2) ? 1.f : -1.f;
  const float shx = (s & 1) ? 1.f : -1.f;
  const float rxy = 1.f / 256.f;
  float l0 = __fadd_rn(loc0 + shy * rxy, 1e-6f);
  float l1 = __fadd_rn(loc1 + shx * rxy, 1e-6f);
  const float lo = -1.f + 1e-6f, hi = 1.f - 1e-6f;
  l0 = fminf(fmaxf(l0, lo), hi);
  l1 = fminf(fmaxf(l1, lo), hi);
  iy = (int)rintf(__fmul_rn(__fadd_rn(__fmul_rn(__fadd_rn(l0, 1.f), 256.f), -1.f), 0.5f));
  ix = (int)rintf(__fmul_rn(__fadd_rn(__fmul_rn(__fadd_rn(l1, 1.f), 256.f), -1.f), 0.5f));
  iy = min(max(iy, 0), 255);
  ix = min(max(ix, 0), 255);
  const float qy = -1.f + (float)(2 * iy + 1) * (1.f / 256.f);
  const float qx = -1.f + (float)(2 * ix + 1) * (1.f / 256.f);
  rel0v = __fmul_rn(__fsub_rn(loc0, qy), 256.f);
  rel1v = __fmul_rn(__fsub_rn(loc1, qx), 256.f);
  c0v = cell[q * 2 + 0] * 256.f;
  c1v = cell[q * 2 + 1] * 256.f;
}

// prefetch next layer's step-0 A-frags (issued before the epilogue barriers)
template <int KW>
__device__ __forceinline__ void prefA(const _Float16* __restrict__ wt,
                                      int w, int lane, half8* pa) {
  const int m = lane & 31, qd = lane >> 5;
  const _Float16* base = wt + (w * 64 + m) * KW + qd * 8;
  pa[0] = *(const half8*)(base);
  pa[1] = *(const half8*)(base + 32 * KW);
}

// ---------------------------------------------------------------------------
// One layer, 32x32x16: acc[ft][rt] += W-frag (A, m=feature) x act-frag (B).
// A[m=lane&31][k=qd*8+j] from L2; B[k=qd*8+j][n=lane&31] from swizzled LDS.
// D: col=lane&31 (act row), row=(reg&3)+8*(reg>>2)+4*qd (feature) [m74/m101].
// ---------------------------------------------------------------------------
template <int NSTEPS, int KW>
__device__ __forceinline__ void layer_mm32(const _Float16* __restrict__ wt,
                                           f32x16 acc[2][4],
                                           const _Float16* sA, int w, int lane,
                                           const half8* pa) {
  const int m = lane & 31, qd = lane >> 5, e = lane & 7;
  const _Float16* ab0 = wt + (w * 64 + m) * KW + qd * 8;
  const _Float16* bb[4];
#pragma unroll
  for (int rt = 0; rt < 4; ++rt) bb[rt] = sA + (rt * 32 + m) * SA;  // row&7==lane&7
#pragma unroll
  for (int st = 0; st < NSTEPS; ++st) {
    const int off = ((st * 2 + qd) ^ e) * 8;
    half8 a[2], b[4];
    if (st == 0) {
      a[0] = pa[0]; a[1] = pa[1];
    } else {
      a[0] = *(const half8*)(ab0 + st * 16);
      a[1] = *(const half8*)(ab0 + 32 * KW + st * 16);
    }
#pragma unroll
    for (int rt = 0; rt < 4; ++rt) b[rt] = *(const half8*)(bb[rt] + off);
#pragma unroll
    for (int ft = 0; ft < 2; ++ft)
#pragma unroll
      for (int rt = 0; rt < 4; ++rt)
        acc[ft][rt] = __builtin_amdgcn_mfma_f32_32x32x16_f16(a[ft], b[rt],
                                                             acc[ft][rt], 0, 0, 0);
  }
}

// bias + ReLU, write act back in-place as swizzled half4 b64 stores.
__device__ __forceinline__ void epilogue32(f32x16 acc[2][4], _Float16* sA,
                                           const float* __restrict__ bias,
                                           int w, int lane) {
  __syncthreads();                          // all waves done reading this layer's act
  const int n = lane & 31, qd = lane >> 5;
#pragma unroll
  for (int ft = 0; ft < 2; ++ft) {
    const int fbase = w * 64 + ft * 32;
#pragma unroll
    for (int g = 0; g < 4; ++g) {
      const int f0 = fbase + g * 8 + qd * 4;      // 4 consecutive features
      const f32x4 bv = *(const f32x4*)(bias + f0);
      const int chunk = (fbase >> 3) + g;         // (fbase+g*8)>>3 ; qd only in f&7
#pragma unroll
      for (int rt = 0; rt < 4; ++rt) {
        const int row = rt * 32 + n;
        half4 h;
#pragma unroll
        for (int r = 0; r < 4; ++r) {
          h[r] = (_Float16)fmaxf(acc[ft][rt][g * 4 + r] + bv[r], 0.f);
          acc[ft][rt][g * 4 + r] = 0.f;
        }
        const int pos = chunk ^ (row & 7);
        *(half4*)(sA + row * SA + pos * 8 + qd * 4) = h;
      }
    }
  }
  __syncthreads();                          // writes visible before next layer reads
}

// ---------------------------------------------------------------------------
// Main fused kernel: 1 block = 128 rows = 32 queries; LDS = 80 KB act buffer.
// ---------------------------------------------------------------------------
__global__ __launch_bounds__(256, 2) void liif_main(
    const _Float16* __restrict__ featT,
    const float* __restrict__ loc, const float* __restrict__ cell,
    const float* __restrict__ b1, const float* __restrict__ b2,
    const float* __restrict__ b3, const float* __restrict__ b4,
    const float* __restrict__ b5,
    const _Float16* __restrict__ wt1, const _Float16* __restrict__ wt2,
    const _Float16* __restrict__ wt3, const _Float16* __restrict__ wt4,
    const _Float16* __restrict__ wt5,
    float* __restrict__ out) {
  extern __shared__ __align__(16) _Float16 sAct[];

  const int tid = threadIdx.x;
  const int w = tid >> 6, lane = tid & 63;
  const int blk = blockIdx.x;

  half8 pa[2];
  prefA<320>(wt1, w, lane, pa);             // overlap L2 latency with the gather

  // ---- gather: thread = (row, half-of-channels); params computed in-regs ----
  {
    const int row = tid >> 1, part = tid & 1;
    int iy, ix; float rel0v, rel1v, c0v, c1v;
    row_params(blk * MROW + row, loc, cell, iy, ix, rel0v, rel1v, c0v, c1v);
    const int y0 = (iy == 0) ? 1 : iy - 1;
    const int y2 = (iy == 255) ? 254 : iy + 1;
    const int x0 = (ix == 0) ? 1 : ix - 1;
    const int x2 = (ix == 255) ? 254 : ix + 1;
    _Float16* arow = sAct + row * SA;
    const int eor = row & 7;
#pragma unroll
    for (int k = 0; k < 9; ++k) {
      const int dy = k / 3, dx = k % 3;
      const int y = (dy == 0) ? y0 : ((dy == 1) ? iy : y2);
      const int x = (dx == 0) ? x0 : ((dx == 1) ? ix : x2);
      const half8* src = (const half8*)(featT + ((y << 8) + x) * 32 + part * 16);
#pragma unroll
      for (int j = 0; j < 2; ++j) {
        const int pos = (k * 4 + part * 2 + j) ^ eor;
        *(half8*)(arow + pos * 8) = src[j];
      }
    }
    // tail chunks 36..39 (cols 288..319): rel/cell + zero pad
#pragma unroll
    for (int j = 0; j < 2; ++j) {
      half8 tv = {};
      if (part == 0 && j == 0) {
        tv[0] = (_Float16)rel0v;
        tv[1] = (_Float16)rel1v;
        tv[2] = (_Float16)c0v;
        tv[3] = (_Float16)c1v;
      }
      const int pos = (36 + part * 2 + j) ^ eor;
      *(half8*)(arow + pos * 8) = tv;
    }
  }

  f32x16 acc[2][4];
#pragma unroll
  for (int ft = 0; ft < 2; ++ft)
#pragma unroll
    for (int rt = 0; rt < 4; ++rt)
#pragma unroll
      for (int r = 0; r < 16; ++r) acc[ft][rt][r] = 0.f;

  __syncthreads();

  // ---- MLP layers 1..4 (32x32x16 MFMA, cross-barrier weight prefetch) ----
  layer_mm32<20, 320>(wt1, acc, sAct, w, lane, pa);
  prefA<256>(wt2, w, lane, pa);
  epilogue32(acc, sAct, b1, w, lane);
  layer_mm32<16, 256>(wt2, acc, sAct, w, lane, pa);
  prefA<256>(wt3, w, lane, pa);
  epilogue32(acc, sAct, b2, w, lane);
  layer_mm32<16, 256>(wt3, acc, sAct, w, lane, pa);
  prefA<256>(wt4, w, lane, pa);
  epilogue32(acc, sAct, b3, w, lane);
  layer_mm32<16, 256>(wt4, acc, sAct, w, lane, pa);
  epilogue32(acc, sAct, b4, w, lane);

  // ---- layer 5 (16x16x32, wave-local) + area combine ----
  {
    const int ln = lane & 15, qd = lane >> 4, e = ln & 7;
#pragma unroll
    for (int nt = 0; nt < 2; ++nt) {
      f32x4 a5 = {0.f, 0.f, 0.f, 0.f};
      const _Float16* abp = wt5 + ln * 256 + qd * 8;
      const _Float16* bbp = sAct + (w * 32 + nt * 16 + ln) * SA;  // &7 == ln&7
#pragma unroll
      for (int st = 0; st < 8; ++st) {
        const int off = ((((st << 2) | qd) ^ e) << 3);
        const half8 a = *(const half8*)(abp + st * 32);
        const half8 b = *(const half8*)(bbp + off);
        a5 = __builtin_amdgcn_mfma_f32_16x16x32_f16(a, b, a5, 0, 0, 0);
      }
      int iy, ix; float rel0v, rel1v, c0v, c1v;
      row_params(blk * MROW + w * 32 + nt * 16 + ln, loc, cell,
                 iy, ix, rel0v, rel1v, c0v, c1v);
      const float area = fabsf(rel0v * rel1v) + 1e-9f;
      float t = area + __shfl_xor(area, 1);
      const float tot = t + __shfl_xor(t, 2);
      const float asw = __shfl_xor(area, 3);
      const float wr = asw / tot;
      float v0 = (a5[0] + b5[0]) * wr;
      float v1 = (a5[1] + b5[1]) * wr;
      float v2 = (a5[2] + b5[2]) * wr;
      v0 += __shfl_xor(v0, 1); v0 += __shfl_xor(v0, 2);
      v1 += __shfl_xor(v1, 1); v1 += __shfl_xor(v1, 2);
      v2 += __shfl_xor(v2, 1); v2 += __shfl_xor(v2, 2);
      if (qd == 0 && (ln & 3) == 0) {
        const int q = blk * 32 + w * 8 + nt * 4 + (ln >> 2);
        out[q * 3 + 0] = v0;
        out[q * 3 + 1] = v1;
        out[q * 3 + 2] = v2;
      }
    }
  }
}

// ---------------------------------------------------------------------------
extern "C" void kernel_launch(void* const* d_in, const int* in_sizes, int n_in,
                              void* d_out, int out_size, void* d_ws, size_t ws_size,
                              hipStream_t stream) {
  (void)in_sizes; (void)n_in; (void)out_size; (void)ws_size;
  const float* feat = (const float*)d_in[0];
  const float* loc  = (const float*)d_in[1];
  const float* cell = (const float*)d_in[2];
  const float* w1 = (const float*)d_in[3];  const float* b1 = (const float*)d_in[4];
  const float* w2 = (const float*)d_in[5];  const float* b2 = (const float*)d_in[6];
  const float* w3 = (const float*)d_in[7];  const float* b3 = (const float*)d_in[8];
  const float* w4 = (const float*)d_in[9];  const float* b4 = (const float*)d_in[10];
  const float* w5 = (const float*)d_in[11]; const float* b5 = (const float*)d_in[12];

  char* ws = (char*)d_ws;
  _Float16* featT = (_Float16*)(ws);                    // 4,194,304 B
  _Float16* wt1 = (_Float16*)(ws + 4194304);            //   163,840 B [256][320]
  _Float16* wt2 = (_Float16*)(ws + 4358144);            //   131,072 B [256][256]
  _Float16* wt3 = (_Float16*)(ws + 4489216);            //   131,072 B
  _Float16* wt4 = (_Float16*)(ws + 4620288);            //   131,072 B
  _Float16* wt5 = (_Float16*)(ws + 4751360);            //     8,192 B [16][256]

  liif_prep<<<1360, 256, 0, stream>>>(feat, w1, w2, w3, w4, w5,
                                      featT, wt1, wt2, wt3, wt4, wt5);
  liif_main<<<2048, 256, MROW * SA * 2, stream>>>(featT, loc, cell,
                                                  b1, b2, b3, b4, b5,
                                                  wt1, wt2, wt3, wt4, wt5,
                                                  (float*)d_out);
}